// Round 11
// baseline (838.660 us; speedup 1.0000x reference)
//
#include <hip/hip_runtime.h>

// TSP_GNN: 2x GCNConv(edge-weighted, self-loops) + FC + row softmax.
// N=8192 nodes, E=262144 edges, H=64.
// R8: (a) real gemm1 = R6 structure + per-block k-stagger (channel spread);
// (b) diagnostic kernels appended after pipeline: kd_stall (stage+barrier only),
// kd_comp (compute only), kd_load<0/1> (pure load probe, unstaggered/staggered).
// Diagnostics write nothing (asm-live); they inflate dur_us this round only.

#define NN 8192
#define NE 262144
#define HD 64
#define KCH 1024   // K-chunk per gemm1 block
#define NKC 8      // number of K-chunks

typedef float f32x4 __attribute__((ext_vector_type(4)));
typedef short v8s   __attribute__((ext_vector_type(8)));
typedef unsigned short ushort_t;

#define KEEP4(v) asm volatile("" :: "v"((v)[0]), "v"((v)[1]), "v"((v)[2]), "v"((v)[3]))

__device__ __forceinline__ unsigned short bf16_rne(float f){
  union { float f; unsigned u; } v; v.f = f;
  unsigned r = v.u + 0x7fffu + ((v.u >> 16) & 1u);
  return (unsigned short)(r >> 16);
}
__device__ __forceinline__ float bf16_f32(unsigned short h){
  union { unsigned u; float f; } v; v.u = ((unsigned)h) << 16;
  return v.f;
}
__device__ __forceinline__ f32x4 mfma16(v8s a, v8s b, f32x4 c){
  return __builtin_amdgcn_mfma_f32_16x16x32_bf16(a, b, c, 0, 0, 0);
}
// truncation split: hi = top16(f), lo = bf16(f - hi).
__device__ __forceinline__ void split_tr(float f, short& hi, short& lo){
  unsigned u = __float_as_uint(f);
  hi = (short)(u >> 16);
  float fh = __uint_as_float(u & 0xffff0000u);
  float d = f - fh;
  lo = (short)(__float_as_uint(d) >> 16);
}
// async global->LDS, 16B per lane; lds base wave-uniform.
__device__ __forceinline__ void gload16(const void* g, void* l){
  __builtin_amdgcn_global_load_lds(
      (const __attribute__((address_space(1))) unsigned int*)g,
      (__attribute__((address_space(3))) unsigned int*)l, 16, 0, 0);
}

// ---------------- prep: init + pack W1 (hi/lo, chunk-swizzled) + pack fcW ----
__global__ void k_prep0(const float* __restrict__ W1, const float* __restrict__ fcW,
                        ushort_t* w1hi, ushort_t* w1lo, ushort_t* fcwp,
                        float* deg, int* cnt, int* wcnt, float* S){
  int idx = blockIdx.x*blockDim.x + threadIdx.x;   // 0..524287
  if (idx < NN){ deg[idx]=1.0f; cnt[idx]=0; wcnt[idx]=0; S[idx]=0.0f; }
  {
    int kk = idx & 31, c = (idx>>5)&15, nt = (idx>>9)&3, kb = idx>>11;
    int k = kb*32 + kk, col = nt*16 + c;
    float w = W1[(size_t)k*HD + col];
    unsigned short hi = bf16_rne(w);
    int chunk = idx >> 3, e = idx & 7;
    int sidx = ((chunk ^ (c & 7)) << 3) | e;
    w1hi[sidx] = hi;
    w1lo[sidx] = bf16_rne(w - bf16_f32(hi));
  }
  {
    int kk = idx & 31, c = (idx>>5)&15, cblk = (idx>>9)&511, kb = idx>>18;
    int k = kb*32 + kk, col = cblk*16 + c;
    fcwp[idx] = bf16_rne(fcW[(size_t)k*NN + col]);
  }
}

__global__ void k_deg_cnt(const int* ei, const float* ew, float* deg, int* cnt){
  int e = blockIdx.x*blockDim.x + threadIdx.x;
  if (e < NE){
    int d = ei[NE + e];
    atomicAdd(&deg[d], ew[e]);
    atomicAdd(&cnt[d], 1);
  }
}

__global__ void k_scan(const int* cnt, const float* deg, int* rowptr, float* dinv){
  __shared__ int part[256];
  int t = threadIdx.x;
  int loc[32]; int s = 0;
  #pragma unroll
  for (int j=0;j<32;++j){ loc[j] = cnt[t*32+j]; s += loc[j]; }
  part[t] = s; __syncthreads();
  for (int off=1; off<256; off<<=1){
    int v = (t >= off) ? part[t-off] : 0;
    __syncthreads();
    part[t] += v;
    __syncthreads();
  }
  int run = part[t] - s;
  #pragma unroll
  for (int j=0;j<32;++j){ rowptr[t*32+j] = run; run += loc[j]; }
  if (t == 255) rowptr[NN] = run;
  #pragma unroll
  for (int j=0;j<32;++j) dinv[t*32+j] = 1.0f / sqrtf(deg[t*32+j]);
}

__global__ void k_fill(const int* ei, const float* ew, const float* dinv,
                       const int* rowptr, int* wcnt, int* csr_src, float* csr_nrm){
  int e = blockIdx.x*blockDim.x + threadIdx.x;
  if (e < NE){
    int s = ei[e], d = ei[NE+e];
    int slot = rowptr[d] + atomicAdd(&wcnt[d], 1);
    csr_src[slot] = s;
    csr_nrm[slot] = dinv[s] * ew[e] * dinv[d];
  }
}

// ---------------- GEMM1 (R6 structure + per-block k-stagger) ----------------
__global__ __launch_bounds__(256, 4) void k_gemm1(const float* __restrict__ X,
                                                  const ushort_t* __restrict__ w1hi,
                                                  const ushort_t* __restrict__ w1lo,
                                                  float* __restrict__ xw1p){
  __shared__ __align__(16) char bufA[2][64*128];
  __shared__ __align__(16) char bufBh[2][4096];
  __shared__ __align__(16) char bufBl[2][4096];
  int tid = threadIdx.x, lane = tid & 63, w = tid >> 6;
  int r = lane & 15, seg = lane >> 4;
  int l8 = lane >> 3, l7 = lane & 7;
  int row0 = blockIdx.x*64;
  int kb0 = blockIdx.y * KCH;
  int tstag = (blockIdx.x*5 + blockIdx.y) & 31;   // channel-spread stagger

  const char* Xb = (const char*)X;
  size_t asrc0 = ((size_t)(row0 + w*16 +     l8) << 15) + ((size_t)(l7 ^ l8) << 4) + ((size_t)kb0 << 2);
  size_t asrc1 = ((size_t)(row0 + w*16 + 8 + l8) << 15) + ((size_t)(l7 ^ l8) << 4) + ((size_t)kb0 << 2);
  const char* bhb = (const char*)w1hi + ((size_t)(kb0 >> 5) << 12) + w*1024 + lane*16;
  const char* blb = (const char*)w1lo + ((size_t)(kb0 >> 5) << 12) + w*1024 + lane*16;

  f32x4 z = {0.f,0.f,0.f,0.f};
  f32x4 acc[4] = {z,z,z,z};

  int arow = (w*16 + r)*128;
  int ac0 = ((seg*2    ) ^ (r & 7)) << 4;
  int ac1 = ((seg*2 + 1) ^ (r & 7)) << 4;
  int bc[4];
  #pragma unroll
  for (int nt=0; nt<4; ++nt)
    bc[nt] = ((nt*64 + r*4 + seg) ^ (r & 7)) << 4;

  const int NT = KCH/32;   // 32 steps

  {
    int te = tstag;                       // t_eff(0)
    gload16(Xb + asrc0 + (size_t)te*128, &bufA[0][w*2048]);
    gload16(Xb + asrc1 + (size_t)te*128, &bufA[0][w*2048 + 1024]);
    gload16(bhb + (size_t)te*4096, &bufBh[0][w*1024]);
    gload16(blb + (size_t)te*4096, &bufBl[0][w*1024]);
  }
  __syncthreads();

  for (int t = 0; t < NT; ++t){
    int cur = t & 1;
    if (t + 1 < NT){
      int te = (t + 1 + tstag) & 31;
      gload16(Xb + asrc0 + (size_t)te*128, &bufA[cur^1][w*2048]);
      gload16(Xb + asrc1 + (size_t)te*128, &bufA[cur^1][w*2048 + 1024]);
      gload16(bhb + (size_t)te*4096, &bufBh[cur^1][w*1024]);
      gload16(blb + (size_t)te*4096, &bufBl[cur^1][w*1024]);
    }
    f32x4 a0 = *(const f32x4*)(&bufA[cur][arow + ac0]);
    f32x4 a1 = *(const f32x4*)(&bufA[cur][arow + ac1]);
    v8s ah, al;
    #pragma unroll
    for (int j=0;j<4;++j){
      short h,l;
      split_tr(a0[j], h, l); ah[j]   = h; al[j]   = l;
      split_tr(a1[j], h, l); ah[4+j] = h; al[4+j] = l;
    }
    #pragma unroll
    for (int nt=0; nt<4; ++nt){
      v8s bh = *(const v8s*)(&bufBh[cur][bc[nt]]);
      v8s bl = *(const v8s*)(&bufBl[cur][bc[nt]]);
      acc[nt] = mfma16(ah, bh, acc[nt]);
      acc[nt] = mfma16(ah, bl, acc[nt]);
      acc[nt] = mfma16(al, bh, acc[nt]);
    }
    __syncthreads();
  }

  float* o = xw1p + (size_t)blockIdx.y*(NN*HD) + (size_t)(row0 + w*16)*HD;
  #pragma unroll
  for (int nt=0; nt<4; ++nt)
    #pragma unroll
    for (int j=0;j<4;++j)
      o[(4*seg + j)*HD + nt*16 + r] = acc[nt][j];
}

// ---------------- diagnostics (write nothing; asm-live) ----------------
// v1: stage + barrier + ds_read, NO compute. 2 reps. Unstaggered (diagnoses R6).
__global__ __launch_bounds__(256, 4) void kd_stall(const float* __restrict__ X,
                                                   const ushort_t* __restrict__ w1hi,
                                                   const ushort_t* __restrict__ w1lo){
  __shared__ __align__(16) char bufA[2][64*128];
  __shared__ __align__(16) char bufBh[2][4096];
  __shared__ __align__(16) char bufBl[2][4096];
  int lane = threadIdx.x & 63, w = threadIdx.x >> 6;
  int r = lane & 15, seg = lane >> 4;
  int l8 = lane >> 3, l7 = lane & 7;
  int row0 = blockIdx.x*64, kb0 = blockIdx.y*KCH;
  const char* Xb = (const char*)X;
  size_t asrc0 = ((size_t)(row0 + w*16 +     l8) << 15) + ((size_t)(l7 ^ l8) << 4) + ((size_t)kb0 << 2);
  size_t asrc1 = ((size_t)(row0 + w*16 + 8 + l8) << 15) + ((size_t)(l7 ^ l8) << 4) + ((size_t)kb0 << 2);
  const char* bhb = (const char*)w1hi + ((size_t)(kb0 >> 5) << 12) + w*1024 + lane*16;
  const char* blb = (const char*)w1lo + ((size_t)(kb0 >> 5) << 12) + w*1024 + lane*16;
  int arow = (w*16 + r)*128;
  int ac0 = ((seg*2    ) ^ (r & 7)) << 4;
  int ac1 = ((seg*2 + 1) ^ (r & 7)) << 4;
  int bc[4];
  #pragma unroll
  for (int nt=0; nt<4; ++nt)
    bc[nt] = ((nt*64 + r*4 + seg) ^ (r & 7)) << 4;

  for (int rep = 0; rep < 2; ++rep){
    gload16(Xb + asrc0, &bufA[0][w*2048]);
    gload16(Xb + asrc1, &bufA[0][w*2048 + 1024]);
    gload16(bhb, &bufBh[0][w*1024]);
    gload16(blb, &bufBl[0][w*1024]);
    __syncthreads();
    for (int t = 0; t < 32; ++t){
      int cur = t & 1;
      if (t + 1 < 32){
        gload16(Xb + asrc0 + (size_t)(t+1)*128, &bufA[cur^1][w*2048]);
        gload16(Xb + asrc1 + (size_t)(t+1)*128, &bufA[cur^1][w*2048 + 1024]);
        gload16(bhb + (size_t)(t+1)*4096, &bufBh[cur^1][w*1024]);
        gload16(blb + (size_t)(t+1)*4096, &bufBl[cur^1][w*1024]);
      }
      f32x4 a0 = *(const f32x4*)(&bufA[cur][arow + ac0]);
      f32x4 a1 = *(const f32x4*)(&bufA[cur][arow + ac1]);
      KEEP4(a0); KEEP4(a1);
      #pragma unroll
      for (int nt=0; nt<4; ++nt){
        f32x4 bh = *(const f32x4*)(&bufBh[cur][bc[nt]]);
        f32x4 bl = *(const f32x4*)(&bufBl[cur][bc[nt]]);
        KEEP4(bh); KEEP4(bl);
      }
      __syncthreads();
    }
  }
}

// v2: compute + barriers, NO global traffic. 3 reps.
__global__ __launch_bounds__(256, 4) void kd_comp(){
  __shared__ __align__(16) char bufA[2][64*128];
  __shared__ __align__(16) char bufBh[2][4096];
  __shared__ __align__(16) char bufBl[2][4096];
  int tid = threadIdx.x, lane = tid & 63, w = tid >> 6;
  int r = lane & 15, seg = lane >> 4;
  { int* p = (int*)bufA;  for (int o = tid; o < 4096; o += 256) p[o] = 0; }
  { int* p = (int*)bufBh; for (int o = tid; o < 2048; o += 256) p[o] = 0; }
  { int* p = (int*)bufBl; for (int o = tid; o < 2048; o += 256) p[o] = 0; }
  __syncthreads();
  int arow = (w*16 + r)*128;
  int ac0 = ((seg*2    ) ^ (r & 7)) << 4;
  int ac1 = ((seg*2 + 1) ^ (r & 7)) << 4;
  int bc[4];
  #pragma unroll
  for (int nt=0; nt<4; ++nt)
    bc[nt] = ((nt*64 + r*4 + seg) ^ (r & 7)) << 4;
  f32x4 z = {0.f,0.f,0.f,0.f};
  f32x4 acc[4] = {z,z,z,z};
  for (int rep = 0; rep < 3; ++rep){
    for (int t = 0; t < 32; ++t){
      int cur = t & 1;
      f32x4 a0 = *(const f32x4*)(&bufA[cur][arow + ac0]);
      f32x4 a1 = *(const f32x4*)(&bufA[cur][arow + ac1]);
      v8s ah, al;
      #pragma unroll
      for (int j=0;j<4;++j){
        short h,l;
        split_tr(a0[j], h, l); ah[j]   = h; al[j]   = l;
        split_tr(a1[j], h, l); ah[4+j] = h; al[4+j] = l;
      }
      #pragma unroll
      for (int nt=0; nt<4; ++nt){
        v8s bh = *(const v8s*)(&bufBh[cur][bc[nt]]);
        v8s bl = *(const v8s*)(&bufBl[cur][bc[nt]]);
        acc[nt] = mfma16(ah, bh, acc[nt]);
        acc[nt] = mfma16(ah, bl, acc[nt]);
        acc[nt] = mfma16(al, bh, acc[nt]);
      }
      __syncthreads();
    }
  }
  #pragma unroll
  for (int nt=0; nt<4; ++nt) KEEP4(acc[nt]);
}

// v3/v4: pure load probe of R6's global pattern. STAG=0: lockstep; STAG=1: staggered.
// Depth-4 register pipeline, no LDS, no barriers. 2 reps.
template<int STAG>
__global__ __launch_bounds__(256, 4) void kd_load(const float* __restrict__ X,
                                                  const ushort_t* __restrict__ w1hi,
                                                  const ushort_t* __restrict__ w1lo){
  int lane = threadIdx.x & 63, w = threadIdx.x >> 6;
  int l8 = lane >> 3, l7 = lane & 7;
  int row0 = blockIdx.x*64, kb0 = blockIdx.y*KCH;
  int tstag = STAG ? ((blockIdx.x*5 + blockIdx.y) & 31) : 0;
  const char* Xb = (const char*)X;
  size_t asrc0 = ((size_t)(row0 + w*16 +     l8) << 15) + ((size_t)(l7 ^ l8) << 4) + ((size_t)kb0 << 2);
  size_t asrc1 = ((size_t)(row0 + w*16 + 8 + l8) << 15) + ((size_t)(l7 ^ l8) << 4) + ((size_t)kb0 << 2);
  const char* bhb = (const char*)w1hi + ((size_t)(kb0 >> 5) << 12) + w*1024 + lane*16;
  const char* blb = (const char*)w1lo + ((size_t)(kb0 >> 5) << 12) + w*1024 + lane*16;
  for (int rep = 0; rep < 2; ++rep){
    asm volatile("" ::: "memory");
    f32x4 sA0[4], sA1[4], sB0[4], sB1[4];
    #pragma unroll
    for (int p = 0; p < 4; ++p){
      int te = (p + tstag) & 31;
      sA0[p] = *(const f32x4*)(Xb + asrc0 + (size_t)te*128);
      sA1[p] = *(const f32x4*)(Xb + asrc1 + (size_t)te*128);
      sB0[p] = *(const f32x4*)(bhb + (size_t)te*4096);
      sB1[p] = *(const f32x4*)(blb + (size_t)te*4096);
    }
    #pragma unroll
    for (int t = 0; t < 32; ++t){
      int s = t & 3;
      KEEP4(sA0[s]); KEEP4(sA1[s]); KEEP4(sB0[s]); KEEP4(sB1[s]);
      if (t + 4 < 32){
        int te = (t + 4 + tstag) & 31;
        sA0[s] = *(const f32x4*)(Xb + asrc0 + (size_t)te*128);
        sA1[s] = *(const f32x4*)(Xb + asrc1 + (size_t)te*128);
        sB0[s] = *(const f32x4*)(bhb + (size_t)te*4096);
        sB1[s] = *(const f32x4*)(blb + (size_t)te*4096);
      }
    }
  }
}

// reduce NKC partial planes -> xw1
__global__ __launch_bounds__(256) void k_red(const float* __restrict__ xw1p,
                                             float* __restrict__ xw1){
  int i = blockIdx.x*blockDim.x + threadIdx.x;
  f32x4 s = {0.f,0.f,0.f,0.f};
  #pragma unroll
  for (int c=0;c<NKC;++c){
    f32x4 v = *(const f32x4*)(xw1p + (size_t)c*NN*HD + (size_t)i*4);
    s[0]+=v[0]; s[1]+=v[1]; s[2]+=v[2]; s[3]+=v[3];
  }
  *(f32x4*)(xw1 + (size_t)i*4) = s;
}

// ---------------- agg1 + conv2 fused ----------------
__global__ __launch_bounds__(256) void k_agg1c(const float* __restrict__ xin,
                                               const float* __restrict__ b1,
                                               const float* __restrict__ W2,
                                               const float* __restrict__ dinv,
                                               const int* __restrict__ rowptr,
                                               const int* __restrict__ csr_src,
                                               const float* __restrict__ csr_nrm,
                                               float* __restrict__ x2w){
  __shared__ float W2s[64*64];
  __shared__ float rows[4][64];
  int lane = threadIdx.x & 63, w = threadIdx.x >> 6;
  for (int o = threadIdx.x; o < 64*64; o += 256) W2s[o] = W2[o];
  __syncthreads();

  int i = blockIdx.x*4 + w;
  float di = dinv[i];
  float acc = di*di * xin[(size_t)i*HD + lane];
  int e = rowptr[i], e1 = rowptr[i+1];
  for (; e + 1 < e1; e += 2){
    int s0 = csr_src[e], s1 = csr_src[e+1];
    float n0 = csr_nrm[e], n1 = csr_nrm[e+1];
    acc += n0 * xin[(size_t)s0*HD + lane];
    acc += n1 * xin[(size_t)s1*HD + lane];
  }
  if (e < e1) acc += csr_nrm[e] * xin[(size_t)csr_src[e]*HD + lane];
  float v = acc + b1[lane];
  rows[w][lane] = v > 0.f ? v : 0.f;
  __syncthreads();

  float acc2 = 0.f;
  #pragma unroll
  for (int k=0;k<64;++k) acc2 += rows[w][k] * W2s[k*64 + lane];
  x2w[(size_t)i*HD + lane] = acc2;
}

// ---------------- agg2 -> bf16 ----------------
__global__ __launch_bounds__(256) void k_agg2(const float* __restrict__ xin,
                                              const float* __restrict__ b2,
                                              const float* __restrict__ dinv,
                                              const int* __restrict__ rowptr,
                                              const int* __restrict__ csr_src,
                                              const float* __restrict__ csr_nrm,
                                              ushort_t* __restrict__ x2b){
  int lane = threadIdx.x & 63, w = threadIdx.x >> 6;
  int i = blockIdx.x*4 + w;
  float di = dinv[i];
  float acc = di*di * xin[(size_t)i*HD + lane];
  int e = rowptr[i], e1 = rowptr[i+1];
  for (; e + 1 < e1; e += 2){
    int s0 = csr_src[e], s1 = csr_src[e+1];
    float n0 = csr_nrm[e], n1 = csr_nrm[e+1];
    acc += n0 * xin[(size_t)s0*HD + lane];
    acc += n1 * xin[(size_t)s1*HD + lane];
  }
  if (e < e1) acc += csr_nrm[e] * xin[(size_t)csr_src[e]*HD + lane];
  float v = acc + b2[lane];
  v = v > 0.f ? v : 0.f;
  x2b[(size_t)i*HD + lane] = bf16_rne(v);
}

// ---------------- FC + softmax, swapped-operand MFMA ----------------
__global__ __launch_bounds__(256) void k_rowsum(const ushort_t* __restrict__ x2b,
                                                const ushort_t* __restrict__ fcwp,
                                                const float* __restrict__ fcb,
                                                float* __restrict__ S){
  int lane = threadIdx.x & 63, w = threadIdx.x >> 6;
  int r = lane & 15, seg = lane >> 4;
  int row0 = blockIdx.x*128 + w*32;
  const ushort_t* xb = x2b + (size_t)(row0 + r)*HD + seg*8;
  v8s x00 = *(const v8s*)(xb);
  v8s x01 = *(const v8s*)(xb + 32);
  v8s x10 = *(const v8s*)(xb + 16*HD);
  v8s x11 = *(const v8s*)(xb + 16*HD + 32);
  float rp0 = 0.f, rp1 = 0.f;
  for (int cb=0; cb<4; ++cb){
    int colbase = blockIdx.y*256 + cb*64;
    f32x4 z = {0.f,0.f,0.f,0.f};
    f32x4 acc0[4] = {z,z,z,z}, acc1[4] = {z,z,z,z};
    #pragma unroll
    for (int nt=0; nt<4; ++nt){
      int cblk = (colbase >> 4) + nt;
      v8s bA = *(const v8s*)(fcwp + ((size_t)cblk*16 + r)*32 + seg*8);
      v8s bB = *(const v8s*)(fcwp + ((size_t)(512 + cblk)*16 + r)*32 + seg*8);
      acc0[nt] = mfma16(bA, x00, acc0[nt]);
      acc0[nt] = mfma16(bB, x01, acc0[nt]);
      acc1[nt] = mfma16(bA, x10, acc1[nt]);
      acc1[nt] = mfma16(bB, x11, acc1[nt]);
    }
    #pragma unroll
    for (int nt=0; nt<4; ++nt){
      int col = colbase + nt*16 + seg*4;
      f32x4 fb = *(const f32x4*)(fcb + col);
      #pragma unroll
      for (int j=0;j<4;++j){
        rp0 += __expf(acc0[nt][j] + fb[j]);
        rp1 += __expf(acc1[nt][j] + fb[j]);
      }
    }
  }
  rp0 += __shfl_xor(rp0, 16); rp0 += __shfl_xor(rp0, 32);
  rp1 += __shfl_xor(rp1, 16); rp1 += __shfl_xor(rp1, 32);
  if (lane < 16){
    atomicAdd(&S[row0 + lane],      rp0);
    atomicAdd(&S[row0 + 16 + lane], rp1);
  }
}

__global__ __launch_bounds__(256) void k_passB(const ushort_t* __restrict__ x2b,
                                               const ushort_t* __restrict__ fcwp,
                                               const float* __restrict__ fcb,
                                               const float* __restrict__ S,
                                               float* __restrict__ out){
  int lane = threadIdx.x & 63, w = threadIdx.x >> 6;
  int r = lane & 15, seg = lane >> 4;
  int row0 = blockIdx.x*128 + w*32;
  const ushort_t* xb = x2b + (size_t)(row0 + r)*HD + seg*8;
  v8s x00 = *(const v8s*)(xb);
  v8s x01 = *(const v8s*)(xb + 32);
  v8s x10 = *(const v8s*)(xb + 16*HD);
  v8s x11 = *(const v8s*)(xb + 16*HD + 32);
  float si0 = 1.0f / S[row0 + r];
  float si1 = 1.0f / S[row0 + 16 + r];
  float* o0 = out + (size_t)(row0 + r)*NN;
  float* o1 = out + (size_t)(row0 + 16 + r)*NN;
  for (int cb=0; cb<4; ++cb){
    int colbase = blockIdx.y*256 + cb*64;
    f32x4 z = {0.f,0.f,0.f,0.f};
    f32x4 acc0[4] = {z,z,z,z}, acc1[4] = {z,z,z,z};
    #pragma unroll
    for (int nt=0; nt<4; ++nt){
      int cblk = (colbase >> 4) + nt;
      v8s bA = *(const v8s*)(fcwp + ((size_t)cblk*16 + r)*32 + seg*8);
      v8s bB = *(const v8s*)(fcwp + ((size_t)(512 + cblk)*16 + r)*32 + seg*8);
      acc0[nt] = mfma16(bA, x00, acc0[nt]);
      acc0[nt] = mfma16(bB, x01, acc0[nt]);
      acc1[nt] = mfma16(bA, x10, acc1[nt]);
      acc1[nt] = mfma16(bB, x11, acc1[nt]);
    }
    #pragma unroll
    for (int nt=0; nt<4; ++nt){
      int col = colbase + nt*16 + seg*4;
      f32x4 fb = *(const f32x4*)(fcb + col);
      f32x4 v0, v1;
      #pragma unroll
      for (int j=0;j<4;++j){
        v0[j] = __expf(acc0[nt][j] + fb[j]) * si0;
        v1[j] = __expf(acc1[nt][j] + fb[j]) * si1;
      }
      *(f32x4*)(o0 + col) = v0;
      *(f32x4*)(o1 + col) = v1;
    }
  }
}

// ---------------- host ----------------
extern "C" void kernel_launch(void* const* d_in, const int* in_sizes, int n_in,
                              void* d_out, int out_size, void* d_ws, size_t ws_size,
                              hipStream_t stream){
  (void)in_sizes; (void)n_in; (void)out_size; (void)ws_size;
  const int*   ei  = (const int*)  d_in[0];
  const float* ew  = (const float*)d_in[1];
  const float* X   = (const float*)d_in[2];
  const float* W1  = (const float*)d_in[3];
  const float* b1  = (const float*)d_in[4];
  const float* W2  = (const float*)d_in[5];
  const float* b2  = (const float*)d_in[6];
  const float* fcW = (const float*)d_in[7];
  const float* fcb = (const float*)d_in[8];
  float* out = (float*)d_out;
  char*  ws  = (char*)d_ws;

  float*    deg     = (float*)   (ws + 0);
  float*    dinv    = (float*)   (ws + 32768);
  int*      cnt     = (int*)     (ws + 65536);
  int*      wcnt    = (int*)     (ws + 98304);
  int*      rowptr  = (int*)     (ws + 131072);
  int*      csr_src = (int*)     (ws + 167936);
  float*    csr_nrm = (float*)   (ws + 1216512);
  ushort_t* w1hi    = (ushort_t*)(ws + 2265088);
  ushort_t* w1lo    = (ushort_t*)(ws + 3313664);
  ushort_t* fcwp    = (ushort_t*)(ws + 4362240);
  float*    xw1p    = (float*)   (ws + 5410816);   // NKC * 2 MB = 16 MB
  float*    xw1     = (float*)   (ws + 22188032);
  float*    x2w     = (float*)   (ws + 24285184);
  ushort_t* x2b     = (ushort_t*)(ws + 26382336);
  float*    S       = (float*)   (ws + 27430912);

  k_prep0   <<<2048, 256, 0, stream>>>(W1, fcW, w1hi, w1lo, fcwp, deg, cnt, wcnt, S);
  k_deg_cnt <<<1024, 256, 0, stream>>>(ei, ew, deg, cnt);
  k_scan    <<<1,    256, 0, stream>>>(cnt, deg, rowptr, dinv);
  k_fill    <<<1024, 256, 0, stream>>>(ei, ew, dinv, rowptr, wcnt, csr_src, csr_nrm);
  k_gemm1   <<<dim3(128, NKC), 256, 0, stream>>>(X, w1hi, w1lo, xw1p);
  k_red     <<<512,  256, 0, stream>>>(xw1p, xw1);
  k_agg1c   <<<2048, 256, 0, stream>>>(xw1, b1, W2, dinv, rowptr, csr_src, csr_nrm, x2w);
  k_agg2    <<<2048, 256, 0, stream>>>(x2w, b2, dinv, rowptr, csr_src, csr_nrm, x2b);
  k_rowsum  <<<dim3(64,32), 256, 0, stream>>>(x2b, fcwp, fcb, S);
  k_passB   <<<dim3(64,32), 256, 0, stream>>>(x2b, fcwp, fcb, S, out);

  // ---- diagnostics (no outputs; inflate dur_us this round only) ----
  kd_stall  <<<dim3(128, NKC), 256, 0, stream>>>(X, w1hi, w1lo);
  kd_comp   <<<dim3(128, NKC), 256, 0, stream>>>();
  kd_load<0><<<dim3(128, NKC), 256, 0, stream>>>(X, w1hi, w1lo);
  kd_load<1><<<dim3(128, NKC), 256, 0, stream>>>(X, w1hi, w1lo);
}

// Round 12
// 285.234 us; speedup vs baseline: 2.9403x; 2.9403x over previous
//
#include <hip/hip_runtime.h>

// TSP_GNN: 2x GCNConv(edge-weighted, self-loops) + FC + row softmax.
// N=8192 nodes, E=262144 edges, H=64.
// R9: gemm1 = row-linear LDS staging (512B runs/row via global_load_lds, frag
// transpose at ds_read via chunk-XOR) + counted s_waitcnt vmcnt(16) across raw
// s_barrier (T3/T4): prefetch survives the barrier. 64 rows/block, k-step 128,
// 128 KB dynamic LDS, grid (128,8). Rest of pipeline = R8 (diagnostics removed).

#define NN 8192
#define NE 262144
#define HD 64
#define KCH 1024   // K-chunk per gemm1 block
#define NKC 8      // number of K-chunks
#define KSTEP 128
#define NT (KCH/KSTEP)   // 8 steps

typedef float f32x4 __attribute__((ext_vector_type(4)));
typedef short v8s   __attribute__((ext_vector_type(8)));
typedef unsigned short ushort_t;

__device__ __forceinline__ unsigned short bf16_rne(float f){
  union { float f; unsigned u; } v; v.f = f;
  unsigned r = v.u + 0x7fffu + ((v.u >> 16) & 1u);
  return (unsigned short)(r >> 16);
}
__device__ __forceinline__ float bf16_f32(unsigned short h){
  union { unsigned u; float f; } v; v.u = ((unsigned)h) << 16;
  return v.f;
}
__device__ __forceinline__ f32x4 mfma16(v8s a, v8s b, f32x4 c){
  return __builtin_amdgcn_mfma_f32_16x16x32_bf16(a, b, c, 0, 0, 0);
}
// truncation split: hi = top16(f), lo = bf16(f - hi).
__device__ __forceinline__ void split_tr(float f, short& hi, short& lo){
  unsigned u = __float_as_uint(f);
  hi = (short)(u >> 16);
  float fh = __uint_as_float(u & 0xffff0000u);
  float d = f - fh;
  lo = (short)(__float_as_uint(d) >> 16);
}
// async global->LDS, 16B per lane; lds base wave-uniform, global addr per-lane.
__device__ __forceinline__ void gload16(const void* g, void* l){
  __builtin_amdgcn_global_load_lds(
      (const __attribute__((address_space(1))) unsigned int*)g,
      (__attribute__((address_space(3))) unsigned int*)l, 16, 0, 0);
}

// ---------------- prep: init + pack W1 (hi/lo, chunk-swizzled) + pack fcW ----
// W1 frag layout idx = ((kb*4+nt)*16+c)*32+kk, stored at sidx = ((chunk^(c&7))<<3)|e.
__global__ void k_prep0(const float* __restrict__ W1, const float* __restrict__ fcW,
                        ushort_t* w1hi, ushort_t* w1lo, ushort_t* fcwp,
                        float* deg, int* cnt, int* wcnt, float* S){
  int idx = blockIdx.x*blockDim.x + threadIdx.x;   // 0..524287
  if (idx < NN){ deg[idx]=1.0f; cnt[idx]=0; wcnt[idx]=0; S[idx]=0.0f; }
  {
    int kk = idx & 31, c = (idx>>5)&15, nt = (idx>>9)&3, kb = idx>>11;
    int k = kb*32 + kk, col = nt*16 + c;
    float w = W1[(size_t)k*HD + col];
    unsigned short hi = bf16_rne(w);
    int chunk = idx >> 3, e = idx & 7;
    int sidx = ((chunk ^ (c & 7)) << 3) | e;
    w1hi[sidx] = hi;
    w1lo[sidx] = bf16_rne(w - bf16_f32(hi));
  }
  {
    int kk = idx & 31, c = (idx>>5)&15, cblk = (idx>>9)&511, kb = idx>>18;
    int k = kb*32 + kk, col = cblk*16 + c;
    fcwp[idx] = bf16_rne(fcW[(size_t)k*NN + col]);
  }
}

__global__ void k_deg_cnt(const int* ei, const float* ew, float* deg, int* cnt){
  int e = blockIdx.x*blockDim.x + threadIdx.x;
  if (e < NE){
    int d = ei[NE + e];
    atomicAdd(&deg[d], ew[e]);
    atomicAdd(&cnt[d], 1);
  }
}

__global__ void k_scan(const int* cnt, const float* deg, int* rowptr, float* dinv){
  __shared__ int part[256];
  int t = threadIdx.x;
  int loc[32]; int s = 0;
  #pragma unroll
  for (int j=0;j<32;++j){ loc[j] = cnt[t*32+j]; s += loc[j]; }
  part[t] = s; __syncthreads();
  for (int off=1; off<256; off<<=1){
    int v = (t >= off) ? part[t-off] : 0;
    __syncthreads();
    part[t] += v;
    __syncthreads();
  }
  int run = part[t] - s;
  #pragma unroll
  for (int j=0;j<32;++j){ rowptr[t*32+j] = run; run += loc[j]; }
  if (t == 255) rowptr[NN] = run;
  #pragma unroll
  for (int j=0;j<32;++j) dinv[t*32+j] = 1.0f / sqrtf(deg[t*32+j]);
}

__global__ void k_fill(const int* ei, const float* ew, const float* dinv,
                       const int* rowptr, int* wcnt, int* csr_src, float* csr_nrm){
  int e = blockIdx.x*blockDim.x + threadIdx.x;
  if (e < NE){
    int s = ei[e], d = ei[NE+e];
    int slot = rowptr[d] + atomicAdd(&wcnt[d], 1);
    csr_src[slot] = s;
    csr_nrm[slot] = dinv[s] * ew[e] * dinv[d];
  }
}

// ---------------- GEMM1: xw1p[kc] = X[:, kc] @ W1[kc, :] ----------------
// 4 waves x 16 rows = 64 rows/block; k-step 128.
// A staged row-linear: LDS [row][128k fp32] (512 B/row), 1KB/instr = 2 rows.
// Chunk-XOR (keyed by row&7) applied on SOURCE, inverted at ds_read.
// B staged as 4x 4KB frag slices (R6 pack). Counted vmcnt across raw barriers.
__global__ __launch_bounds__(256, 1) void k_gemm1(const float* __restrict__ X,
                                                  const ushort_t* __restrict__ w1hi,
                                                  const ushort_t* __restrict__ w1lo,
                                                  float* __restrict__ xw1p){
  extern __shared__ __align__(16) char smem[];   // 131072 B
  // A: [0,65536) two 32KB buffers; Bh: [65536,98304); Bl: [98304,131072)
  int lane = threadIdx.x & 63, w = threadIdx.x >> 6;
  int r = lane & 15, seg = lane >> 4;
  int l31 = lane & 31, lhi = lane >> 5;
  int row0 = blockIdx.x*64, kb0 = blockIdx.y*KCH;

  const char* Xb = (const char*)X;
  // A source addresses: instr i covers local rows 16w+2i, 16w+2i+1 (lhi picks),
  // dest chunk cd = l31; source chunk low3 XOR'd by row.
  size_t asrc[8];
  #pragma unroll
  for (int i=0;i<8;++i){
    int rl = w*16 + 2*i + lhi;
    int cs = (l31 & 24) | ((l31 ^ rl) & 7);
    asrc[i] = (size_t)(row0 + rl)*(NN*4) + (size_t)kb0*4 + (size_t)cs*16;
  }
  const char* bhBase = (const char*)w1hi;
  const char* blBase = (const char*)w1lo;

  // ds_read addresses
  int aoff[4][2];
  #pragma unroll
  for (int ks=0; ks<4; ++ks)
    #pragma unroll
    for (int j=0; j<2; ++j)
      aoff[ks][j] = (w*16 + r)*512 + (ks*8 + (((seg*2 + j) ^ r) & 7))*16;
  int bc[4];
  #pragma unroll
  for (int nt=0; nt<4; ++nt)
    bc[nt] = ((nt*64 + r*4 + seg) ^ (r & 7)) << 4;

  f32x4 z = {0.f,0.f,0.f,0.f};
  f32x4 acc[4] = {z,z,z,z};

  auto STAGE = [&](int t, int b){
    char* aD = smem + b*32768 + (w*8)*1024;
    size_t ko = (size_t)t*512;                 // 128 floats per step
    #pragma unroll
    for (int i=0;i<8;++i)
      gload16(Xb + asrc[i] + ko, aD + i*1024);
    size_t sB = (size_t)((kb0 >> 5) + t*4 + w) * 4096;
    char* hD = smem + 65536 + b*16384 + w*4096;
    char* lD = smem + 98304 + b*16384 + w*4096;
    #pragma unroll
    for (int i=0;i<4;++i){
      gload16(bhBase + sB + i*1024 + lane*16, hD + i*1024);
      gload16(blBase + sB + i*1024 + lane*16, lD + i*1024);
    }
  };

  STAGE(0, 0);                                 // 16 loads/wave in flight

  for (int t = 0; t < NT; ++t){
    int cur = t & 1;
    if (t + 1 < NT){
      STAGE(t+1, cur^1);                       // +16 -> 32 outstanding
      asm volatile("s_waitcnt vmcnt(16)" ::: "memory");   // step t landed
    } else {
      asm volatile("s_waitcnt vmcnt(0)" ::: "memory");
    }
    __builtin_amdgcn_s_barrier();              // all waves: buf[cur] ready
    __builtin_amdgcn_sched_barrier(0);         // no hoisting above barrier
    const char* A  = smem + cur*32768;
    const char* Bh = smem + 65536 + cur*16384;
    const char* Bl = smem + 98304 + cur*16384;
    #pragma unroll
    for (int ks=0; ks<4; ++ks){
      f32x4 a0 = *(const f32x4*)(A + aoff[ks][0]);
      f32x4 a1 = *(const f32x4*)(A + aoff[ks][1]);
      v8s ah, al;
      #pragma unroll
      for (int j=0;j<4;++j){
        short h,l;
        split_tr(a0[j], h, l); ah[j]   = h; al[j]   = l;
        split_tr(a1[j], h, l); ah[4+j] = h; al[4+j] = l;
      }
      #pragma unroll
      for (int nt=0; nt<4; ++nt){
        v8s bh = *(const v8s*)(Bh + ks*4096 + bc[nt]);
        v8s bl = *(const v8s*)(Bl + ks*4096 + bc[nt]);
        acc[nt] = mfma16(ah, bh, acc[nt]);
        acc[nt] = mfma16(ah, bl, acc[nt]);
        acc[nt] = mfma16(al, bh, acc[nt]);
      }
    }
    __builtin_amdgcn_sched_barrier(0);
    __builtin_amdgcn_s_barrier();              // protect buf[cur] from stage(t+2)
  }

  // D layout: row-within-16 = 4*seg+j, col = nt*16+r
  float* o = xw1p + (size_t)blockIdx.y*(NN*HD) + (size_t)(row0 + w*16)*HD;
  #pragma unroll
  for (int nt=0; nt<4; ++nt)
    #pragma unroll
    for (int j=0;j<4;++j)
      o[(4*seg + j)*HD + nt*16 + r] = acc[nt][j];
}

// reduce NKC partial planes -> xw1
__global__ __launch_bounds__(256) void k_red(const float* __restrict__ xw1p,
                                             float* __restrict__ xw1){
  int i = blockIdx.x*blockDim.x + threadIdx.x;   // over NN*HD/4
  f32x4 s = {0.f,0.f,0.f,0.f};
  #pragma unroll
  for (int c=0;c<NKC;++c){
    f32x4 v = *(const f32x4*)(xw1p + (size_t)c*NN*HD + (size_t)i*4);
    s[0]+=v[0]; s[1]+=v[1]; s[2]+=v[2]; s[3]+=v[3];
  }
  *(f32x4*)(xw1 + (size_t)i*4) = s;
}

// ---------------- agg1 + conv2 fused ----------------
__global__ __launch_bounds__(256) void k_agg1c(const float* __restrict__ xin,
                                               const float* __restrict__ b1,
                                               const float* __restrict__ W2,
                                               const float* __restrict__ dinv,
                                               const int* __restrict__ rowptr,
                                               const int* __restrict__ csr_src,
                                               const float* __restrict__ csr_nrm,
                                               float* __restrict__ x2w){
  __shared__ float W2s[64*64];
  __shared__ float rows[4][64];
  int lane = threadIdx.x & 63, w = threadIdx.x >> 6;
  for (int o = threadIdx.x; o < 64*64; o += 256) W2s[o] = W2[o];
  __syncthreads();

  int i = blockIdx.x*4 + w;
  float di = dinv[i];
  float acc = di*di * xin[(size_t)i*HD + lane];
  int e = rowptr[i], e1 = rowptr[i+1];
  for (; e + 1 < e1; e += 2){
    int s0 = csr_src[e], s1 = csr_src[e+1];
    float n0 = csr_nrm[e], n1 = csr_nrm[e+1];
    acc += n0 * xin[(size_t)s0*HD + lane];
    acc += n1 * xin[(size_t)s1*HD + lane];
  }
  if (e < e1) acc += csr_nrm[e] * xin[(size_t)csr_src[e]*HD + lane];
  float v = acc + b1[lane];
  rows[w][lane] = v > 0.f ? v : 0.f;
  __syncthreads();

  float acc2 = 0.f;
  #pragma unroll
  for (int k=0;k<64;++k) acc2 += rows[w][k] * W2s[k*64 + lane];
  x2w[(size_t)i*HD + lane] = acc2;
}

// ---------------- agg2 -> bf16 ----------------
__global__ __launch_bounds__(256) void k_agg2(const float* __restrict__ xin,
                                              const float* __restrict__ b2,
                                              const float* __restrict__ dinv,
                                              const int* __restrict__ rowptr,
                                              const int* __restrict__ csr_src,
                                              const float* __restrict__ csr_nrm,
                                              ushort_t* __restrict__ x2b){
  int lane = threadIdx.x & 63, w = threadIdx.x >> 6;
  int i = blockIdx.x*4 + w;
  float di = dinv[i];
  float acc = di*di * xin[(size_t)i*HD + lane];
  int e = rowptr[i], e1 = rowptr[i+1];
  for (; e + 1 < e1; e += 2){
    int s0 = csr_src[e], s1 = csr_src[e+1];
    float n0 = csr_nrm[e], n1 = csr_nrm[e+1];
    acc += n0 * xin[(size_t)s0*HD + lane];
    acc += n1 * xin[(size_t)s1*HD + lane];
  }
  if (e < e1) acc += csr_nrm[e] * xin[(size_t)csr_src[e]*HD + lane];
  float v = acc + b2[lane];
  v = v > 0.f ? v : 0.f;
  x2b[(size_t)i*HD + lane] = bf16_rne(v);
}

// ---------------- FC + softmax, swapped-operand MFMA ----------------
__global__ __launch_bounds__(256) void k_rowsum(const ushort_t* __restrict__ x2b,
                                                const ushort_t* __restrict__ fcwp,
                                                const float* __restrict__ fcb,
                                                float* __restrict__ S){
  int lane = threadIdx.x & 63, w = threadIdx.x >> 6;
  int r = lane & 15, seg = lane >> 4;
  int row0 = blockIdx.x*128 + w*32;
  const ushort_t* xb = x2b + (size_t)(row0 + r)*HD + seg*8;
  v8s x00 = *(const v8s*)(xb);
  v8s x01 = *(const v8s*)(xb + 32);
  v8s x10 = *(const v8s*)(xb + 16*HD);
  v8s x11 = *(const v8s*)(xb + 16*HD + 32);
  float rp0 = 0.f, rp1 = 0.f;
  for (int cb=0; cb<4; ++cb){
    int colbase = blockIdx.y*256 + cb*64;
    f32x4 z = {0.f,0.f,0.f,0.f};
    f32x4 acc0[4] = {z,z,z,z}, acc1[4] = {z,z,z,z};
    #pragma unroll
    for (int nt=0; nt<4; ++nt){
      int cblk = (colbase >> 4) + nt;
      v8s bA = *(const v8s*)(fcwp + ((size_t)cblk*16 + r)*32 + seg*8);
      v8s bB = *(const v8s*)(fcwp + ((size_t)(512 + cblk)*16 + r)*32 + seg*8);
      acc0[nt] = mfma16(bA, x00, acc0[nt]);
      acc0[nt] = mfma16(bB, x01, acc0[nt]);
      acc1[nt] = mfma16(bA, x10, acc1[nt]);
      acc1[nt] = mfma16(bB, x11, acc1[nt]);
    }
    #pragma unroll
    for (int nt=0; nt<4; ++nt){
      int col = colbase + nt*16 + seg*4;
      f32x4 fb = *(const f32x4*)(fcb + col);
      #pragma unroll
      for (int j=0;j<4;++j){
        rp0 += __expf(acc0[nt][j] + fb[j]);
        rp1 += __expf(acc1[nt][j] + fb[j]);
      }
    }
  }
  rp0 += __shfl_xor(rp0, 16); rp0 += __shfl_xor(rp0, 32);
  rp1 += __shfl_xor(rp1, 16); rp1 += __shfl_xor(rp1, 32);
  if (lane < 16){
    atomicAdd(&S[row0 + lane],      rp0);
    atomicAdd(&S[row0 + 16 + lane], rp1);
  }
}

__global__ __launch_bounds__(256) void k_passB(const ushort_t* __restrict__ x2b,
                                               const ushort_t* __restrict__ fcwp,
                                               const float* __restrict__ fcb,
                                               const float* __restrict__ S,
                                               float* __restrict__ out){
  int lane = threadIdx.x & 63, w = threadIdx.x >> 6;
  int r = lane & 15, seg = lane >> 4;
  int row0 = blockIdx.x*128 + w*32;
  const ushort_t* xb = x2b + (size_t)(row0 + r)*HD + seg*8;
  v8s x00 = *(const v8s*)(xb);
  v8s x01 = *(const v8s*)(xb + 32);
  v8s x10 = *(const v8s*)(xb + 16*HD);
  v8s x11 = *(const v8s*)(xb + 16*HD + 32);
  float si0 = 1.0f / S[row0 + r];
  float si1 = 1.0f / S[row0 + 16 + r];
  float* o0 = out + (size_t)(row0 + r)*NN;
  float* o1 = out + (size_t)(row0 + 16 + r)*NN;
  for (int cb=0; cb<4; ++cb){
    int colbase = blockIdx.y*256 + cb*64;
    f32x4 z = {0.f,0.f,0.f,0.f};
    f32x4 acc0[4] = {z,z,z,z}, acc1[4] = {z,z,z,z};
    #pragma unroll
    for (int nt=0; nt<4; ++nt){
      int cblk = (colbase >> 4) + nt;
      v8s bA = *(const v8s*)(fcwp + ((size_t)cblk*16 + r)*32 + seg*8);
      v8s bB = *(const v8s*)(fcwp + ((size_t)(512 + cblk)*16 + r)*32 + seg*8);
      acc0[nt] = mfma16(bA, x00, acc0[nt]);
      acc0[nt] = mfma16(bB, x01, acc0[nt]);
      acc1[nt] = mfma16(bA, x10, acc1[nt]);
      acc1[nt] = mfma16(bB, x11, acc1[nt]);
    }
    #pragma unroll
    for (int nt=0; nt<4; ++nt){
      int col = colbase + nt*16 + seg*4;
      f32x4 fb = *(const f32x4*)(fcb + col);
      f32x4 v0, v1;
      #pragma unroll
      for (int j=0;j<4;++j){
        v0[j] = __expf(acc0[nt][j] + fb[j]) * si0;
        v1[j] = __expf(acc1[nt][j] + fb[j]) * si1;
      }
      *(f32x4*)(o0 + col) = v0;
      *(f32x4*)(o1 + col) = v1;
    }
  }
}

// ---------------- host ----------------
extern "C" void kernel_launch(void* const* d_in, const int* in_sizes, int n_in,
                              void* d_out, int out_size, void* d_ws, size_t ws_size,
                              hipStream_t stream){
  (void)in_sizes; (void)n_in; (void)out_size; (void)ws_size;
  const int*   ei  = (const int*)  d_in[0];
  const float* ew  = (const float*)d_in[1];
  const float* X   = (const float*)d_in[2];
  const float* W1  = (const float*)d_in[3];
  const float* b1  = (const float*)d_in[4];
  const float* W2  = (const float*)d_in[5];
  const float* b2  = (const float*)d_in[6];
  const float* fcW = (const float*)d_in[7];
  const float* fcb = (const float*)d_in[8];
  float* out = (float*)d_out;
  char*  ws  = (char*)d_ws;

  float*    deg     = (float*)   (ws + 0);
  float*    dinv    = (float*)   (ws + 32768);
  int*      cnt     = (int*)     (ws + 65536);
  int*      wcnt    = (int*)     (ws + 98304);
  int*      rowptr  = (int*)     (ws + 131072);
  int*      csr_src = (int*)     (ws + 167936);
  float*    csr_nrm = (float*)   (ws + 1216512);
  ushort_t* w1hi    = (ushort_t*)(ws + 2265088);
  ushort_t* w1lo    = (ushort_t*)(ws + 3313664);
  ushort_t* fcwp    = (ushort_t*)(ws + 4362240);
  float*    xw1p    = (float*)   (ws + 5410816);   // NKC * 2 MB = 16 MB
  float*    xw1     = (float*)   (ws + 22188032);
  float*    x2w     = (float*)   (ws + 24285184);
  ushort_t* x2b     = (ushort_t*)(ws + 26382336);
  float*    S       = (float*)   (ws + 27430912);

  // allow 128 KB dynamic LDS for k_gemm1 (set once; proven graph-safe in R7)
  static bool attr_set = false;
  if (!attr_set){
    hipFuncSetAttribute((const void*)k_gemm1,
                        hipFuncAttributeMaxDynamicSharedMemorySize, 131072);
    attr_set = true;
  }

  k_prep0   <<<2048, 256, 0, stream>>>(W1, fcW, w1hi, w1lo, fcwp, deg, cnt, wcnt, S);
  k_deg_cnt <<<1024, 256, 0, stream>>>(ei, ew, deg, cnt);
  k_scan    <<<1,    256, 0, stream>>>(cnt, deg, rowptr, dinv);
  k_fill    <<<1024, 256, 0, stream>>>(ei, ew, dinv, rowptr, wcnt, csr_src, csr_nrm);
  k_gemm1   <<<dim3(128, NKC), 256, 131072, stream>>>(X, w1hi, w1lo, xw1p);
  k_red     <<<512,  256, 0, stream>>>(xw1p, xw1);
  k_agg1c   <<<2048, 256, 0, stream>>>(xw1, b1, W2, dinv, rowptr, csr_src, csr_nrm, x2w);
  k_agg2    <<<2048, 256, 0, stream>>>(x2w, b2, dinv, rowptr, csr_src, csr_nrm, x2b);
  k_rowsum  <<<dim3(64,32), 256, 0, stream>>>(x2b, fcwp, fcb, S);
  k_passB   <<<dim3(64,32), 256, 0, stream>>>(x2b, fcwp, fcb, S, out);
}